// Round 1
// baseline (149.299 us; speedup 1.0000x reference)
//
#include <hip/hip_runtime.h>

// Fused 4x upsample (two polyphase 2x stages composed): out[t] = sum_n g[t-2-4n] x[n],
// g = f (*) up2(f), 67 taps, circular. g is symmetric: tapA[k]=tapA[16-k] pairing via sG,
// phases of out col/row t mod 4: 0 -> 12-tap (tC6), 1 -> 17-tap (tapA), 2 -> copy, 3 -> tapA reversed.
// This version: g computed inline (no separate dispatch), float4 patch loads (non-wrap tiles),
// horizontal pass reads sIn via 5 aligned ds_read_b128 per 4 output quads (was 17 ds_read_b32 per quad).

#define SINS 52      // sIn row stride (48 used + 4 pad; multiple of 4 floats for b128 alignment)
#define SMS 132      // sMid row stride (128 + 4 pad)

__device__ inline void fma4(float4& a, float t, const float4& r) {
    a.x += t * r.x; a.y += t * r.y; a.z += t * r.z; a.w += t * r.w;
}

__global__ __launch_bounds__(256, 4) void up4_fused(
    const float* __restrict__ in, const float* __restrict__ kern,
    float* __restrict__ out) {
    __shared__ float sG[80];
    __shared__ __attribute__((aligned(16))) float sMid[48][SMS];
    __shared__ __attribute__((aligned(16))) float sIn[48][SINS];

    const int tid = threadIdx.x;
    const int tX = blockIdx.x, tY = blockIdx.y, ch = blockIdx.z;
    const int W4 = 1024;

    // ---- compute g = f (*) up2(f) inline, threads 0..79: sG[u] = g[u-34] ----
    if (tid < 80) {
        const int s = tid - 34;
        int jlo = (s - 10) >> 1;        // ceil((s-11)/2)
        int jhi = (s + 11) >> 1;        // floor((s+11)/2)
        if (jlo < -11) jlo = -11;
        if (jhi > 11) jhi = 11;
        float acc = 0.f;
        for (int j = jlo; j <= jhi; ++j)
            acc += kern[11 + s - 2 * j] * kern[11 + j];
        sG[tid] = acc;
    }

    // ---- load 48x48 input patch (sIn[0..47][0..47]), circular wrap via &255 ----
    const float* inC = in + (size_t)ch * 256 * 256;
    const int N0y = 32 * tY - 9, N0x = 32 * tX - 9;
    const int gj0 = (N0x + 1) & 255;    // always ≡ 0 (mod 8) -> float4-aligned
    if (gj0 <= 208) {
        // fast path: 48-col x-range is contiguous (no wrap): 48 rows x 12 float4
#pragma unroll
        for (int it = 0; it < 3; ++it) {
            const int idx = tid + it * 256;         // 0..575
            if (idx < 576) {
                const int pi = idx / 12, m = idx % 12;
                const int gi = (N0y + 1 + pi + 256) & 255;
                *(float4*)&sIn[pi][4 * m] =
                    *(const float4*)&inC[gi * 256 + gj0 + 4 * m];
            }
        }
    } else {
        // wrap path (tX = 0 or 7): scalar with per-element wrap
#pragma unroll
        for (int it = 0; it < 9; ++it) {
            const int idx = tid + it * 256;         // 0..2303
            const int pi = idx / 48, pj = idx % 48;
            const int gi = (N0y + 1 + pi + 256) & 255;
            const int gj = (N0x + 1 + pj + 256) & 255;
            sIn[pi][pj] = inC[gi * 256 + gj];
        }
    }
    __syncthreads();

    // ---- taps in registers (g symmetric -> 23 regs), LDS broadcast reads ----
    float tapA[17], tC6[6];
#pragma unroll
    for (int k = 0; k < 17; ++k) tapA[k] = sG[1 + 4 * k];
#pragma unroll
    for (int m = 0; m < 6; ++m) tC6[m] = sG[12 + 4 * m];

    // ---- horizontal polyphase: 48 rows x 8 thread-strips, 4 quads/thread ----
    // window sIn[row][4t .. 4t+19] covers quads c = 4t..4t+3 (c+16-k in [c, c+16])
#pragma unroll
    for (int it = 0; it < 2; ++it) {
        const int idx = tid + it * 256;             // 0..383
        if (idx < 384) {
            const int t4 = 4 * (idx & 7), row = idx >> 3;
            float win[20];
#pragma unroll
            for (int m = 0; m < 5; ++m)
                *(float4*)&win[4 * m] = *(const float4*)&sIn[row][t4 + 4 * m];
#pragma unroll
            for (int q = 0; q < 4; ++q) {
                float a0 = 0.f, a1 = 0.f, a2 = 0.f, a3 = 0.f;
#pragma unroll
                for (int k = 0; k < 17; ++k) {
                    const float w = win[q + 16 - k];
                    a1 += tapA[k] * w;
                    a3 += tapA[16 - k] * w;
                    if (k >= 3 && k <= 14) {
                        const int m2 = k - 3;
                        a0 += tC6[m2 < 6 ? m2 : 11 - m2] * w;
                    }
                    if (k == 8) a2 = w;
                }
                float4 v; v.x = a0; v.y = a1; v.z = a2; v.w = a3;
                *(float4*)&sMid[row][4 * (t4 + q)] = v;
            }
        }
    }
    __syncthreads();

    // ---- vertical polyphase: 4 row-groups/thread, rolling 20-row window ----
    const int c = tid & 31, gp = tid >> 5;          // c: col-quad, gp: group-of-4-rowgroups
    float4 A[4][4];                                  // A[i][phase]
#pragma unroll
    for (int i = 0; i < 4; ++i)
#pragma unroll
        for (int p = 0; p < 4; ++p) { A[i][p].x = 0.f; A[i][p].y = 0.f; A[i][p].z = 0.f; A[i][p].w = 0.f; }

#pragma unroll
    for (int d = 1; d <= 20; ++d) {
        const float4 R = *(const float4*)&sMid[4 * gp + d - 1][4 * c];
#pragma unroll
        for (int i = 0; i < 4; ++i) {
            const int k = i + 17 - d;               // tap index for row-group 4*gp+i
            if (k < 0 || k > 16) continue;
            fma4(A[i][1], tapA[k], R);
            fma4(A[i][3], tapA[16 - k], R);
            if (k >= 3 && k <= 14) {
                const int m = k - 3;
                fma4(A[i][0], tC6[m < 6 ? m : 11 - m], R);
            }
            if (k == 8) A[i][2] = R;                // copy phase: g[0]=1 exactly
        }
    }

    float* outC = out + (size_t)ch * 1024 * 1024;
    const int row0 = 128 * tY + 16 * gp, col = 128 * tX + 4 * c;
#pragma unroll
    for (int i = 0; i < 4; ++i)
#pragma unroll
        for (int p = 0; p < 4; ++p)
            *(float4*)&outC[(size_t)(row0 + 4 * i + p) * W4 + col] = A[i][p];
}

extern "C" void kernel_launch(void* const* d_in, const int* in_sizes, int n_in,
                              void* d_out, int out_size, void* d_ws, size_t ws_size,
                              hipStream_t stream) {
    const float* x    = (const float*)d_in[0];   // (32, 256, 256)
    const float* kern = (const float*)d_in[1];   // 23 taps
    float* out  = (float*)d_out;                 // (32, 1024, 1024)

    dim3 grid(8, 8, 32);                         // 128x128 output tiles
    up4_fused<<<grid, dim3(256), 0, stream>>>(x, kern, out);
}